// Round 9
// baseline (158.609 us; speedup 1.0000x reference)
//
#include <hip/hip_runtime.h>

#define BB 16
#define CC 80
#define DD 1024
#define HW 196
#define NSP (BB * HW)        // 3136 = 49 full waves, zero lane waste
#define NCH 8                // d-chunks of 128
#define DCH 128
#define CPB 4                // classes per scores block
#define NCQ (CC / CPB)       // 20 class-groups -> grid 2080 blocks
#define PCG 8                // classes per pool block (R0 had 4)
#define TWO_LOG2E 2.8853900817779268f

// ---------------- K1: scores (R0-proven, bitwise-identical) + imgT -----------
__global__ __launch_bounds__(256) void scores_k(const float* __restrict__ img,
                                                const float* __restrict__ word,
                                                const float* __restrict__ fa,
                                                float* __restrict__ partial,
                                                float* __restrict__ imgT) {
    const int g = blockIdx.x * 256 + threadIdx.x;
    if (g >= NSP) return;                           // wave-uniform exit
    const int b  = g / HW;
    const int hw = g - b * HW;
    const int d0 = blockIdx.y * DCH;
    const int c0 = blockIdx.z * CPB;

    const float* ip = img + ((size_t)b * DD + d0) * HW + hw;

    float p[CPB];
#pragma unroll
    for (int k = 0; k < CPB; ++k) p[k] = 0.f;

    for (int q = 0; q < DCH / 32; ++q) {            // 4 quarters of 32 d
        float iv[32];
        const float* qp = ip + (size_t)q * 32 * HW;
#pragma unroll
        for (int i = 0; i < 32; ++i)
            iv[i] = qp[(size_t)i * HW];

        if (blockIdx.z == 0) {                       // block-uniform branch
            float4* tp = (float4*)(imgT + (size_t)g * DD + d0 + q * 32);
#pragma unroll
            for (int i = 0; i < 8; ++i)
                tp[i] = make_float4(iv[4 * i], iv[4 * i + 1], iv[4 * i + 2], iv[4 * i + 3]);
        }

#pragma unroll
        for (int i = 0; i < 32; ++i)
            iv[i] *= TWO_LOG2E;                      // exp2(iv*w) == e^{2x}

        const float* fp = fa + d0 + q * 32;          // uniform -> SGPRs
#pragma unroll
        for (int k = 0; k < CPB; ++k) {
            const float* wp = word + (size_t)(c0 + k) * DD + d0 + q * 32;
            float p0 = 0.f, p1 = 0.f;
#pragma unroll
            for (int i = 0; i < 32; i += 2) {
                float y0 = iv[i]     * wp[i];
                float y1 = iv[i + 1] * wp[i + 1];
                float e0 = __builtin_amdgcn_exp2f(y0);
                float e1 = __builtin_amdgcn_exp2f(y1);
                float r0 = __builtin_amdgcn_rcpf(e0 + 1.f);
                float r1 = __builtin_amdgcn_rcpf(e1 + 1.f);
                p0 = fmaf(fp[i],     r0, p0);
                p1 = fmaf(fp[i + 1], r1, p1);
            }
            p[k] += p0 + p1;
        }
    }

#pragma unroll
    for (int k = 0; k < CPB; ++k)
        partial[(((size_t)b * NCH + blockIdx.y) * CC + (c0 + k)) * HW + hw]
            = (-TWO_LOG2E) * p[k];
}

// ---------------- K2: fused softmax + pooling, 8 classes/block ---------------
// pool2's exact structure with cg 4 -> 8: grid (16 b, 4 dt of 256, 10 cg of 8)
// = 640 blocks x 4 waves = 10 waves/CU (above the ~5 w/CU latency cliff seen
// in pool5/6). imgT L3 re-read factor 20 -> 10: 257 MB -> 128 MB at the
// measured ~3.9 TB/s tier. Per 4-h step: 4 coalesced b32 + 8 broadcast
// ds_read_b128 (conflict-free) + 32 FMA, 8 independent acc chains.
__global__ __launch_bounds__(256) void pool8_k(const float* __restrict__ imgT,
                                               const float* __restrict__ partial,
                                               float* __restrict__ out) {
    __shared__ float ct[PCG * HW];                // 6272 B
    const int b   = blockIdx.x;
    const int dt0 = blockIdx.y * 256;
    const int cg  = blockIdx.z * PCG;
    const int t   = threadIdx.x;
    const int w   = t >> 6, l = t & 63;

    // ---- Phase S: wave w -> softmax of classes cg+w, cg+w+4 (pool4-proven) --
#pragma unroll
    for (int cc = 0; cc < 2; ++cc) {
        const int o = w + 4 * cc;                 // class offset 0..7
        const int c = cg + o;

        float x0 = 0.f, x1 = 0.f, x2 = 0.f, x3 = 0.f;
#pragma unroll
        for (int ch = 0; ch < NCH; ++ch) {
            const float* pp = partial + (((size_t)b * NCH + ch) * CC + c) * HW;
            x0 += pp[l];
            x1 += pp[l + 64];
            x2 += pp[l + 128];
            if (l < HW - 192) x3 += pp[l + 192];
        }
        float x3m = (l < HW - 192) ? x3 : -3.4e38f;

        float m = fmaxf(fmaxf(x0, x1), fmaxf(x2, x3m));
#pragma unroll
        for (int off = 32; off >= 1; off >>= 1) m = fmaxf(m, __shfl_xor(m, off, 64));

        float e0 = __builtin_amdgcn_exp2f(x0 - m);
        float e1 = __builtin_amdgcn_exp2f(x1 - m);
        float e2 = __builtin_amdgcn_exp2f(x2 - m);
        float e3 = (l < HW - 192) ? __builtin_amdgcn_exp2f(x3 - m) : 0.f;

        float s = (e0 + e1) + (e2 + e3);
#pragma unroll
        for (int off = 32; off >= 1; off >>= 1) s += __shfl_xor(s, off, 64);

        float inv = __builtin_amdgcn_rcpf(s);
        float* cr = ct + o * HW;
        cr[l]       = e0 * inv;
        cr[l + 64]  = e1 * inv;
        cr[l + 128] = e2 * inv;
        if (l < HW - 192) cr[l + 192] = e3 * inv;
    }
    __syncthreads();

    // ---- Phase P: thread owns d = dt0 + t, 8 classes ----
    const float* ib = imgT + (size_t)b * HW * DD + dt0 + t;

    float acc[PCG];
#pragma unroll
    for (int k = 0; k < PCG; ++k) acc[k] = 0.f;

#pragma unroll 7
    for (int h = 0; h < HW; h += 4) {
        float i0 = ib[(size_t)(h    ) * DD];
        float i1 = ib[(size_t)(h + 1) * DD];
        float i2 = ib[(size_t)(h + 2) * DD];
        float i3 = ib[(size_t)(h + 3) * DD];
#pragma unroll
        for (int k = 0; k < PCG; ++k) {
            float4 cv = *(const float4*)(ct + k * HW + h);   // broadcast b128
            acc[k] = fmaf(cv.x, i0, fmaf(cv.y, i1, fmaf(cv.z, i2, fmaf(cv.w, i3, acc[k]))));
        }
    }

    float* ob = out + ((size_t)b * CC + cg) * DD + dt0 + t;
#pragma unroll
    for (int k = 0; k < PCG; ++k)
        ob[(size_t)k * DD] = acc[k];
}

extern "C" void kernel_launch(void* const* d_in, const int* in_sizes, int n_in,
                              void* d_out, int out_size, void* d_ws, size_t ws_size,
                              hipStream_t stream) {
    // inputs: [0]=batch_size(int,1) [1]=img [2]=word [3]=fc_a_w [4]=fc_a_b
    const float* img  = (const float*)d_in[1];
    const float* word = (const float*)d_in[2];
    const float* fa   = (const float*)d_in[3];
    float* out = (float*)d_out;

    // workspace (floats): partial[16][8][80][196] = 8.03 MB
    //                   | imgT[3136][1024]        = 12.85 MB  (20.88 MB, proven)
    float* partial = (float*)d_ws;
    float* imgT    = partial + (size_t)BB * NCH * CC * HW;

    scores_k<<<dim3((NSP + 255) / 256, NCH, NCQ), 256, 0, stream>>>(img, word, fa, partial, imgT);
    pool8_k<<<dim3(BB, DD / 256, CC / PCG), 256, 0, stream>>>(imgT, partial, out);
}